// Round 5
// baseline (104.907 us; speedup 1.0000x reference)
//
#include <hip/hip_runtime.h>
#include <hip/hip_bf16.h>

// Problem dims
#define X_B 8
#define X_C 64
#define X_H 64
#define X_W 64
#define X_S 12
// x index: (((b*64 + c)*64 + h)*64 + w)*12 + t
// h-row stride = 768 floats, channel stride = 49152 floats

// Scratch layout inside d_out (floats):
//   [0,1600)                : Weff[c'*25 + tap]
//   [4096, 4096+16*393216)  : partial A_k, layout [q][tg][ (b*64+h)*64+w ][4t] (float4)
#define WEFF_OFF 0
#define PART_OFF 4096
#define PART_SZ  393216   // per q: 3 tg * 32768 bhw * 4 t
#define TG_SZ    131072   // 32768 * 4 floats
// d_ws: p[((b*64+h)*64+w)*12 + t]  (393216 floats = 1.57 MB)

// ---------------------------------------------------------------------------
// K1: fold 1x1-conv (key half of w1) into the 5x5 conv weights.
__global__ __launch_bounds__(256) void k_prep(const float* __restrict__ w1,
                                              const float* __restrict__ w2,
                                              float* __restrict__ weff) {
    int idx = blockIdx.x * 256 + threadIdx.x;
    if (idx >= 64 * 25) return;
    int cp = idx / 25, tap = idx % 25;
    float s = 0.f;
    for (int c = 0; c < 64; ++c)
        s = fmaf(w2[(64 + c) * 25 + tap], w1[(64 + c) * 64 + cp], s);
    weff[cp * 25 + tap] = s;
}

// ---------------------------------------------------------------------------
// K2 (v5): LDS-staged 5x5x64 conv, re-tiled for minimal LDS read traffic.
// Thread = (wp 0..31, hq 0..3, tg 0..2): owns 2 w x 4 rows x 4 t.
// Per input row: 6 ds_read_b128 (slot window) feed 40 FMA (16.7 FMA/read,
// 2x v3). Slot XOR-swizzle s^=(s>>3)&1 breaks the 2-slot-stride bank pileup
// (halo slots 0,1,66,67 are fixed points). 384 thr, 512 blocks, 2 blk/CU.
#define PLANE 5444          // floats per tg plane: 20*272 + 4 pad
#define ROWP  272           // floats per row: 68 slots * 4
#define NSTG  3840          // staged float4s per channel: 20 rows * 192
__global__ __launch_bounds__(384) void k_conv(const float* __restrict__ x,
                                              const float* __restrict__ weff,
                                              float* __restrict__ part) {
    __shared__ float lds[3 * PLANE];   // 65,328 B

    const int bid   = blockIdx.x;
    const int b     = bid & 7;
    const int strip = (bid >> 3) & 3;
    const int q     = bid >> 5;          // 0..15

    const int tid = threadIdx.x;
    const int wp  = tid & 31;            // w-pair: owns w = 2wp, 2wp+1
    const int hq  = (tid >> 5) & 3;      // row quad: owns rows hq*4..hq*4+3
    const int tg  = tid >> 7;            // t-quad 0..2
    const int r0  = strip * 16 - 2;      // global row of LDS row 0

    // zero the w-halo slots (0,1,66,67; swizzle fixed points) once
    if (tid < 240) {
        const int pl  = tid / 80;
        const int rem = tid % 80;
        const int row = rem >> 2;
        const int sl  = rem & 3;
        const int slot = (sl < 2) ? sl : 64 + sl;   // 0,1,66,67
        float4 z; z.x = 0.f; z.y = 0.f; z.z = 0.f; z.w = 0.f;
        *(float4*)(lds + pl * PLANE + row * ROWP + slot * 4) = z;
    }

    // staging addresses: 3840 quads / 384 thr = 10 each, computed once
    int ldsoff[10], gloff[10];
#pragma unroll
    for (int k = 0; k < 10; ++k) {
        const int i   = tid + k * 384;
        const int row = i / 192;
        const int j   = i - row * 192;       // float4 idx in global row
        const int wj  = j / 3;               // w value
        const int tgw = j - wj * 3;          // t-quad
        int sl = wj + 2;
        sl ^= (sl >> 3) & 1;                 // bank swizzle
        ldsoff[k] = tgw * PLANE + row * ROWP + sl * 4;
        const int rg = r0 + row;
        gloff[k] = ((unsigned)rg < 64u) ? (rg * 768 + j * 4) : -1;
    }

    // compute-read window bases: 6 slots starting at 2wp (swizzled), own tg
    const float* base[6];
#pragma unroll
    for (int k = 0; k < 6; ++k) {
        int s = 2 * wp + k;
        s ^= (s >> 3) & 1;
        base[k] = lds + tg * PLANE + (hq * 4) * ROWP + s * 4;
    }

    const float* xb = x + (size_t)(b * 64 + q * 4) * 49152;  // channel q*4

    float acc[4][2][4];   // [oo][j][t]
#pragma unroll
    for (int o = 0; o < 4; ++o)
#pragma unroll
        for (int j = 0; j < 2; ++j)
#pragma unroll
            for (int t = 0; t < 4; ++t) acc[o][j][t] = 0.f;

    // prefetch channel 0
    float4 pf[10];
#pragma unroll
    for (int k = 0; k < 10; ++k) {
        float4 v; v.x = 0.f; v.y = 0.f; v.z = 0.f; v.w = 0.f;
        if (gloff[k] >= 0) v = *(const float4*)(xb + gloff[k]);
        pf[k] = v;
    }

    for (int ci = 0; ci < 4; ++ci) {
        // write staged channel to LDS
#pragma unroll
        for (int k = 0; k < 10; ++k)
            *(float4*)(lds + ldsoff[k]) = pf[k];
        __syncthreads();

        // prefetch next channel while computing this one
        if (ci < 3) {
            const float* xc = xb + (size_t)(ci + 1) * 49152;
#pragma unroll
            for (int k = 0; k < 10; ++k) {
                float4 v; v.x = 0.f; v.y = 0.f; v.z = 0.f; v.w = 0.f;
                if (gloff[k] >= 0) v = *(const float4*)(xc + gloff[k]);
                pf[k] = v;
            }
        }

        // weights: wave-uniform scalar loads
        const float* wgp = weff + (q * 4 + ci) * 25;
        float wgt[25];
#pragma unroll
        for (int k = 0; k < 25; ++k) wgt[k] = wgp[k];

        // 8 input rows; 6-slot window per row; 40 FMA per (rr,oo)
#pragma unroll
        for (int rr = 0; rr < 8; ++rr) {
            float4 v[6];
#pragma unroll
            for (int k = 0; k < 6; ++k)
                v[k] = *(const float4*)(base[k] + rr * ROWP);
            const int olo = (rr - 4 < 0) ? 0 : rr - 4;
            const int ohi = (rr > 3) ? 3 : rr;
#pragma unroll
            for (int oo = olo; oo <= ohi; ++oo) {
                const int dh = rr - oo;
#pragma unroll
                for (int j = 0; j < 2; ++j) {
#pragma unroll
                    for (int dw = 0; dw < 5; ++dw) {
                        const float g = wgt[dh * 5 + dw];
                        const float4 vv = v[j + dw];
                        acc[oo][j][0] = fmaf(g, vv.x, acc[oo][j][0]);
                        acc[oo][j][1] = fmaf(g, vv.y, acc[oo][j][1]);
                        acc[oo][j][2] = fmaf(g, vv.z, acc[oo][j][2]);
                        acc[oo][j][3] = fmaf(g, vv.w, acc[oo][j][3]);
                    }
                }
            }
        }
        __syncthreads();   // protect LDS before next channel's writes
    }

    // store partials: [q][tg][bhw] float4
    float* pb = part + (size_t)q * PART_SZ + (size_t)tg * TG_SZ;
#pragma unroll
    for (int oo = 0; oo < 4; ++oo) {
        const int h = strip * 16 + hq * 4 + oo;
#pragma unroll
        for (int j = 0; j < 2; ++j) {
            const int idx = (b * 64 + h) * 64 + 2 * wp + j;
            float4 st;
            st.x = acc[oo][j][0]; st.y = acc[oo][j][1];
            st.z = acc[oo][j][2]; st.w = acc[oo][j][3];
            *(float4*)(pb + (size_t)idx * 4) = st;
        }
    }
}

// ---------------------------------------------------------------------------
// K3: sum the 16 channel-group partials, softmax over t (12), write p to ws.
__global__ __launch_bounds__(256) void k_soft(const float* __restrict__ part,
                                              float* __restrict__ p) {
    const int idx = blockIdx.x * 256 + threadIdx.x;  // (b,h,w) flat, 0..32767
    if (idx >= 32768) return;
    float v[12];
#pragma unroll
    for (int t = 0; t < 12; ++t) v[t] = 0.f;
#pragma unroll
    for (int qg = 0; qg < 16; ++qg) {
        const float* pp = part + (size_t)qg * PART_SZ;
#pragma unroll
        for (int tg = 0; tg < 3; ++tg) {
            float4 t0 = *(const float4*)(pp + (size_t)tg * TG_SZ + (size_t)idx * 4);
            v[tg * 4 + 0] += t0.x; v[tg * 4 + 1] += t0.y;
            v[tg * 4 + 2] += t0.z; v[tg * 4 + 3] += t0.w;
        }
    }
    float m = v[0];
#pragma unroll
    for (int t = 1; t < 12; ++t) m = fmaxf(m, v[t]);
    float s = 0.f;
#pragma unroll
    for (int t = 0; t < 12; ++t) { v[t] = __expf(v[t] - m); s += v[t]; }
    const float inv = 1.f / s;
#pragma unroll
    for (int t = 0; t < 12; ++t) v[t] *= inv;
    float* op = p + (size_t)idx * 12;
    float4 s0; s0.x = v[0]; s0.y = v[1]; s0.z = v[2];  s0.w = v[3];
    float4 s1; s1.x = v[4]; s1.y = v[5]; s1.z = v[6];  s1.w = v[7];
    float4 s2; s2.x = v[8]; s2.y = v[9]; s2.z = v[10]; s2.w = v[11];
    *(float4*)(op)     = s0;
    *(float4*)(op + 4) = s1;
    *(float4*)(op + 8) = s2;
}

// ---------------------------------------------------------------------------
// K4: out[b,c,h,w,s] = W1v · (sum_t p_t * x[:,t]) + b1v, broadcast over s.
// One block per (b,h): 512 threads = 64 w-lanes * 8 channel-groups.
__global__ __launch_bounds__(512) void k_out(const float* __restrict__ x,
                                             const float* __restrict__ w1,
                                             const float* __restrict__ b1,
                                             const float* __restrict__ p,
                                             float* __restrict__ out) {
    __shared__ float lds[64 * 65];   // [w][c], padded -> conflict-free

    const int b  = blockIdx.x >> 6;
    const int h  = blockIdx.x & 63;
    const int w  = threadIdx.x & 63;
    const int cg = threadIdx.x >> 6;     // 0..7

    const float* pp = p + (size_t)((b * 64 + h) * 64 + w) * 12;
    float pv[12];
    {
        float4 t0 = *(const float4*)(pp);
        float4 t1 = *(const float4*)(pp + 4);
        float4 t2 = *(const float4*)(pp + 8);
        pv[0] = t0.x; pv[1] = t0.y; pv[2]  = t0.z; pv[3]  = t0.w;
        pv[4] = t1.x; pv[5] = t1.y; pv[6]  = t1.z; pv[7]  = t1.w;
        pv[8] = t2.x; pv[9] = t2.y; pv[10] = t2.z; pv[11] = t2.w;
    }

    const float* xb0 = x + ((size_t)(b * 64 + cg * 8) * 64 + h) * 768 + w * 12;
#pragma unroll
    for (int j = 0; j < 8; ++j) {
        const float* xp = xb0 + (size_t)j * 49152;
        float4 u0 = *(const float4*)(xp);
        float4 u1 = *(const float4*)(xp + 4);
        float4 u2 = *(const float4*)(xp + 8);
        float s = 0.f;
        s = fmaf(pv[0], u0.x, s);  s = fmaf(pv[1], u0.y, s);
        s = fmaf(pv[2], u0.z, s);  s = fmaf(pv[3], u0.w, s);
        s = fmaf(pv[4], u1.x, s);  s = fmaf(pv[5], u1.y, s);
        s = fmaf(pv[6], u1.z, s);  s = fmaf(pv[7], u1.w, s);
        s = fmaf(pv[8], u2.x, s);  s = fmaf(pv[9], u2.y, s);
        s = fmaf(pv[10], u2.z, s); s = fmaf(pv[11], u2.w, s);
        lds[w * 65 + cg * 8 + j] = s;
    }
    __syncthreads();

    const float* w1v = w1 + 128 * 64 + cg * 8 * 64;
    float acc[8];
#pragma unroll
    for (int j = 0; j < 8; ++j) acc[j] = b1[128 + cg * 8 + j];
    for (int c2 = 0; c2 < 64; ++c2) {
        const float xv = lds[w * 65 + c2];
#pragma unroll
        for (int j = 0; j < 8; ++j)
            acc[j] = fmaf(w1v[j * 64 + c2], xv, acc[j]);
    }

#pragma unroll
    for (int j = 0; j < 8; ++j) {
        const int co = cg * 8 + j;
        float4 f; f.x = acc[j]; f.y = acc[j]; f.z = acc[j]; f.w = acc[j];
        float* op = out + ((size_t)(b * 64 + co) * 4096 + h * 64 + w) * 12;
        *(float4*)(op)     = f;
        *(float4*)(op + 4) = f;
        *(float4*)(op + 8) = f;
    }
}

// ---------------------------------------------------------------------------
extern "C" void kernel_launch(void* const* d_in, const int* in_sizes, int n_in,
                              void* d_out, int out_size, void* d_ws, size_t ws_size,
                              hipStream_t stream) {
    const float* x  = (const float*)d_in[0];
    const float* w1 = (const float*)d_in[1];
    const float* b1 = (const float*)d_in[2];
    const float* w2 = (const float*)d_in[3];
    // d_in[4] = b2: constant across the softmax axis -> cancels, unused.

    float* outp = (float*)d_out;
    float* weff = outp + WEFF_OFF;
    float* part = outp + PART_OFF;
    float* p    = (float*)d_ws;

    hipLaunchKernelGGL(k_prep, dim3(7),    dim3(256), 0, stream, w1, w2, weff);
    hipLaunchKernelGGL(k_conv, dim3(512),  dim3(384), 0, stream, x, weff, part);
    hipLaunchKernelGGL(k_soft, dim3(128),  dim3(256), 0, stream, part, p);
    hipLaunchKernelGGL(k_out,  dim3(512),  dim3(512), 0, stream, x, w1, b1, p, outp);
}